// Round 2
// baseline (8654.493 us; speedup 1.0000x reference)
//
#include <hip/hip_runtime.h>
#include <math.h>

#define T 65536
#define NCH 32
#define LCHUNK 512
#define CCHUNK 128

// ws layout (float offsets). Total ~17.2 MB of d_ws.
#define OFS_A 0         // 32*65536: biquad out, then compressed (in-place)
#define OFS_B 2097152   // 32*65536: compressor target, then reverb out (in-place)
#define OFS_P 4194304   // 32*64 derived params
#define OFS_M 4196352   // 32*144 chunk transition matrices (columns)
#define OFS_V 4200960   // 32*128*12 chunk zero-state finals
#define OFS_Z 4250112   // 32*128*12 chunk initial states

// ---------------- param kernel (also writes p_out) ----------------

__device__ void norm_store(double b0,double b1,double b2,double a0,double a1,double a2,
                           double* B, double* A1, double* A2, int k){
  B[k*3+0]=b0/a0; B[k*3+1]=b1/a0; B[k*3+2]=b2/a0; A1[k]=a1/a0; A2[k]=a2/a0;
}

__device__ void shelf_coefs(double fc, double g, double s, double* B, double* A1, double* A2, int k){
  double A  = pow(10.0, g/40.0);
  double w  = 2.0*3.14159265358979323846*fc/44100.0;
  double cw = cos(w);
  double al = sin(w)*0.70710678118654752;
  double sq = 2.0*sqrt(A)*al;
  double b0 = A*((A+1.0) + s*(A-1.0)*cw + sq);
  double b1 = -2.0*s*A*((A-1.0) + s*(A+1.0)*cw);
  double b2 = A*((A+1.0) + s*(A-1.0)*cw - sq);
  double a0 = (A+1.0) - s*(A-1.0)*cw + sq;
  double a1 = 2.0*s*((A-1.0) - s*(A+1.0)*cw);
  double a2 = (A+1.0) - s*(A-1.0)*cw - sq;
  norm_store(b0,b1,b2,a0,a1,a2,B,A1,A2,k);
}

__device__ void peak_coefs(double fc, double g, double q, double* B, double* A1, double* A2, int k){
  double A  = pow(10.0, g/40.0);
  double w  = 2.0*3.14159265358979323846*fc/44100.0;
  double cw = cos(w);
  double al = sin(w)/(2.0*q);
  norm_store(1.0+al*A, -2.0*cw, 1.0-al*A, 1.0+al/A, -2.0*cw, 1.0-al/A, B,A1,A2,k);
}

__global__ void k_params(const float* __restrict__ p, float* __restrict__ ws, float* __restrict__ pout){
  int ch = threadIdx.x;
  if (ch >= NCH) return;
  const float* pf = p + ch*24;
  float f[24];
  #pragma unroll
  for (int j=0;j<24;j++) f[j]=pf[j];

  double gain_in = (double)f[0]*60.0 - 48.0;
  double hp_fc  = (double)f[1]*350.0;
  double lp_fc  = (double)f[2]*19000.0 + 3000.0;
  double hs_fc  = (double)f[3]*14500.0 + 1500.0;
  double hs_g   = (double)f[4]*30.0 - 15.0;
  double ls_fc  = (double)f[5]*420.0 + 30.0;
  double ls_g   = (double)f[6]*30.0 - 15.0;
  double mh_fc  = (double)f[7]*6400.0 + 600.0;
  double mh_g   = (double)f[8]*30.0 - 15.0;
  double mh_q   = (double)f[9]*2.5 + 0.5;
  double ml_fc  = (double)f[10]*2300.0 + 200.0;
  double ml_g   = (double)f[11]*30.0 - 15.0;
  double ml_q   = (double)f[12]*2.5 + 0.5;
  double c_thr  = (double)f[13]*30.0 - 20.0;
  double c_rat  = (double)f[14]*19.0 + 1.0;
  double c_att  = (double)f[15]*29.0 + 1.0;
  double c_rel  = (double)f[16]*3900.0 + 100.0;
  double gain_out=(double)f[22]*60.0 - 48.0;
  double pan    = (double)f[23]*0.4 + 0.3;

  double B[18], A1[6], A2[6];
  // section 0: hp
  { double K = tan(3.14159265358979323846*hp_fc/44100.0);
    double a1=(K-1.0)/(K+1.0), b0=1.0/(1.0+K);
    B[0]=b0; B[1]=-b0; B[2]=0.0; A1[0]=a1; A2[0]=0.0; }
  // section 1: lp
  { double K = tan(3.14159265358979323846*lp_fc/44100.0);
    double a1=(K-1.0)/(K+1.0), b0=K/(1.0+K);
    B[3]=b0; B[4]=b0; B[5]=0.0; A1[1]=a1; A2[1]=0.0; }
  shelf_coefs(hs_fc, hs_g,  1.0, B, A1, A2, 2);
  shelf_coefs(ls_fc, ls_g, -1.0, B, A1, A2, 3);
  peak_coefs (mh_fc, mh_g, mh_q, B, A1, A2, 4);
  peak_coefs (ml_fc, ml_g, ml_q, B, A1, A2, 5);

  double gin = pow(10.0, gain_in/20.0);
  B[0]*=gin; B[1]*=gin; B[2]*=gin;  // fold input gain into section 0

  float* Pc = ws + OFS_P + ch*64;
  #pragma unroll
  for (int k=0;k<6;k++){
    Pc[k]    = (float)B[k*3+0];
    Pc[6+k]  = (float)B[k*3+1];
    Pc[12+k] = (float)B[k*3+2];
    Pc[18+k] = (float)A1[k];
    Pc[24+k] = (float)A2[k];
  }
  Pc[30] = (float)c_thr;
  Pc[31] = (float)(1.0 - 1.0/c_rat);
  Pc[32] = (float)exp(-1.0/(c_att*0.001*44100.0));
  Pc[33] = (float)exp(-1.0/(c_rel*0.001*44100.0));
  double fb   = (double)f[17]*0.28 + 0.7;
  double damp = (double)f[18]*0.4;
  double wet1 = 3.0*(double)f[19]*0.5*(1.0+(double)f[21]);
  double dryg = 2.0*(double)f[20];
  double gout = pow(10.0, gain_out/20.0);
  Pc[34] = (float)fb;
  Pc[35] = (float)damp;
  Pc[36] = (float)(wet1*gout);
  Pc[37] = (float)(dryg*gout/0.015);   // applied to (xt*0.015) stored in LDS
  Pc[38] = (float)cos(pan*1.57079632679489662);
  Pc[39] = (float)sin(pan*1.57079632679489662);

  float* po = pout + ch*24;
  po[0]=(float)gain_in; po[1]=(float)hp_fc; po[2]=(float)lp_fc; po[3]=(float)hs_fc;
  po[4]=(float)hs_g; po[5]=(float)ls_fc; po[6]=(float)ls_g; po[7]=(float)mh_fc;
  po[8]=(float)mh_g; po[9]=(float)mh_q; po[10]=(float)ml_fc; po[11]=(float)ml_g;
  po[12]=(float)ml_q; po[13]=(float)c_thr; po[14]=(float)c_rat; po[15]=(float)c_att;
  po[16]=(float)c_rel; po[17]=f[17]; po[18]=f[18]; po[19]=f[19]; po[20]=f[20];
  po[21]=f[21]; po[22]=(float)gain_out; po[23]=(float)pan;
}

// ---------------- biquad cascade: chunked linear scan ----------------

__device__ __forceinline__ float bq_step(const float* b0, const float* b1, const float* b2,
                                         const float* a1, const float* a2,
                                         float* z1, float* z2, float s){
  #pragma unroll
  for (int k=0;k<6;k++){
    float y = fmaf(b0[k], s, z1[k]);
    z1[k] = fmaf(b1[k], s, fmaf(-a1[k], y, z2[k]));
    z2[k] = fmaf(b2[k], s, -a2[k]*y);
    s = y;
  }
  return s;
}

__device__ __forceinline__ void load_coefs(const float* Pc, float* b0, float* b1, float* b2,
                                           float* a1, float* a2){
  #pragma unroll
  for (int k=0;k<6;k++){
    b0[k]=Pc[k]; b1[k]=Pc[6+k]; b2[k]=Pc[12+k]; a1[k]=Pc[18+k]; a2[k]=Pc[24+k];
  }
}

// pass 1: per-chunk zero-state run -> v; unit-state zero-input runs -> M columns
__global__ void k_chunk1(const float* __restrict__ x, float* __restrict__ ws){
  int tg = blockIdx.x*64 + threadIdx.x;      // 32 * 140 tasks
  int ch = tg / 140, sub = tg % 140;
  if (ch >= NCH) return;
  const float* Pc = ws + OFS_P + ch*64;
  float b0[6],b1[6],b2[6],a1[6],a2[6];
  load_coefs(Pc,b0,b1,b2,a1,a2);
  float z1[6]={0,0,0,0,0,0}, z2[6]={0,0,0,0,0,0};

  if (sub < CCHUNK){
    const float4* xp = (const float4*)(x + ch*T + sub*LCHUNK);
    for (int j=0;j<LCHUNK/4;j++){
      float4 v = xp[j];
      bq_step(b0,b1,b2,a1,a2,z1,z2,v.x);
      bq_step(b0,b1,b2,a1,a2,z1,z2,v.y);
      bq_step(b0,b1,b2,a1,a2,z1,z2,v.z);
      bq_step(b0,b1,b2,a1,a2,z1,z2,v.w);
    }
    float* vo = ws + OFS_V + (ch*CCHUNK + sub)*12;
    #pragma unroll
    for (int k=0;k<6;k++){ vo[2*k]=z1[k]; vo[2*k+1]=z2[k]; }
  } else {
    int j = sub - CCHUNK;                    // unit state index 0..11
    if ((j & 1)==0) z1[j>>1]=1.0f; else z2[j>>1]=1.0f;
    for (int t=0;t<LCHUNK;t++) bq_step(b0,b1,b2,a1,a2,z1,z2,0.0f);
    float* mo = ws + OFS_M + ch*144 + j*12;  // column j
    #pragma unroll
    for (int k=0;k<6;k++){ mo[2*k]=z1[k]; mo[2*k+1]=z2[k]; }
  }
}

// pass 2: serial chunk-boundary state propagation (one wave, lane=channel)
__global__ void k_chunk2(float* __restrict__ ws){
  int ch = threadIdx.x;
  if (ch >= NCH) return;
  const float* M = ws + OFS_M + ch*144;
  const float* V = ws + OFS_V + ch*CCHUNK*12;
  float*       Z = ws + OFS_Z + ch*CCHUNK*12;
  float z[12];
  #pragma unroll
  for (int i=0;i<12;i++) z[i]=0.0f;
  for (int c=0;c<CCHUNK;c++){
    #pragma unroll
    for (int i=0;i<12;i++) Z[c*12+i]=z[i];
    float zn[12];
    #pragma unroll
    for (int i=0;i<12;i++) zn[i]=V[c*12+i];
    #pragma unroll
    for (int j=0;j<12;j++){
      float zj = z[j];
      #pragma unroll
      for (int i=0;i<12;i++) zn[i] = fmaf(M[j*12+i], zj, zn[i]);
    }
    #pragma unroll
    for (int i=0;i<12;i++) z[i]=zn[i];
  }
}

// pass 3: re-run chunks with correct init; write biquad out (A) + compressor target (B)
__global__ void k_chunk3(const float* __restrict__ x, float* __restrict__ ws){
  int tg = blockIdx.x*64 + threadIdx.x;      // 4096
  int ch = tg >> 7, c = tg & (CCHUNK-1);
  const float* Pc = ws + OFS_P + ch*64;
  float b0[6],b1[6],b2[6],a1[6],a2[6];
  load_coefs(Pc,b0,b1,b2,a1,a2);
  float thr = Pc[30], rt = Pc[31];
  const float* Zi = ws + OFS_Z + (ch*CCHUNK + c)*12;
  float z1[6], z2[6];
  #pragma unroll
  for (int k=0;k<6;k++){ z1[k]=Zi[2*k]; z2[k]=Zi[2*k+1]; }
  const float4* xp = (const float4*)(x + ch*T + c*LCHUNK);
  float4* Ao = (float4*)(ws + OFS_A + ch*T + c*LCHUNK);
  float4* Bo = (float4*)(ws + OFS_B + ch*T + c*LCHUNK);
  for (int j=0;j<LCHUNK/4;j++){
    float4 v = xp[j], ya, tb;
    ya.x = bq_step(b0,b1,b2,a1,a2,z1,z2,v.x);
    ya.y = bq_step(b0,b1,b2,a1,a2,z1,z2,v.y);
    ya.z = bq_step(b0,b1,b2,a1,a2,z1,z2,v.z);
    ya.w = bq_step(b0,b1,b2,a1,a2,z1,z2,v.w);
    tb.x = fminf(0.0f, (thr - 6.0205999132796239f*log2f(fabsf(ya.x)+1e-6f))*rt);
    tb.y = fminf(0.0f, (thr - 6.0205999132796239f*log2f(fabsf(ya.y)+1e-6f))*rt);
    tb.z = fminf(0.0f, (thr - 6.0205999132796239f*log2f(fabsf(ya.z)+1e-6f))*rt);
    tb.w = fminf(0.0f, (thr - 6.0205999132796239f*log2f(fabsf(ya.w)+1e-6f))*rt);
    Ao[j]=ya; Bo[j]=tb;
  }
}

// ---------------- compressor: exact serial, lane = channel ----------------
// coef = (tgt<g) ? aA : aR, and aA<aR always => g' = min(fma(aA,d,t), fma(aR,d,t))

__global__ void k_comp(float* __restrict__ ws){
  int ch = threadIdx.x;
  if (ch >= NCH) return;
  const float* Pc = ws + OFS_P + ch*64;
  float aA = Pc[32], aR = Pc[33];
  float* Axf = ws + OFS_A + ch*T;
  const float* Bt = ws + OFS_B + ch*T;
  float g = 0.0f;
  #pragma unroll 4
  for (int t=0;t<T;t++){
    float tg = Bt[t];
    float d  = g - tg;
    g = fminf(fmaf(aA,d,tg), fmaf(aR,d,tg));
    Axf[t] = Axf[t] * exp2f(g*0.16609640474436813f);  // 10^(g/20)
  }
}

// ---------------- freeverb: 225-sample time blocks, LDS buffers ----------------

__global__ __launch_bounds__(256) void k_verb(float* __restrict__ ws){
  const int LC[8] = {1116,1188,1277,1356,1422,1491,1557,1617};
  const int COFF[8] = {0,1116,2304,3581,4937,6359,7850,9407};
  const int LA[4] = {556,441,341,225};
  const int AOFF[4] = {0,556,997,1338};
  int ch = blockIdx.x, tid = threadIdx.x;
  __shared__ float cb[11024];
  __shared__ float ab[1563];
  __shared__ float outS[8*225];
  __shared__ float xts[225];
  const float* Pc = ws + OFS_P + ch*64;
  float fb = Pc[34], damp = Pc[35], wet1 = Pc[36], dryk = Pc[37];
  float omd = 1.0f - damp;
  const float* Axf = ws + OFS_A + ch*T;
  float* Bout = ws + OFS_B + ch*T;
  for (int i=tid;i<11024;i+=256) cb[i]=0.0f;
  for (int i=tid;i<1563;i+=256)  ab[i]=0.0f;
  float sreg = 0.0f;
  int cbb[8] = {0,0,0,0,0,0,0,0};
  int abb[4] = {0,0,0,0};
  __syncthreads();

  for (int t0=0; t0<T; t0+=225){
    int Bc = (T - t0 < 225) ? (T - t0) : 225;
    // phase 1: gather comb outputs + input (all pre-block buffer data)
    if (tid < Bc){
      int i = tid;
      xts[i] = Axf[t0+i]*0.015f;
      #pragma unroll
      for (int k=0;k<8;k++){
        int idx = cbb[k]+i; if (idx>=LC[k]) idx-=LC[k];
        outS[k*225+i] = cb[COFF[k]+idx];
      }
    }
    __syncthreads();
    if (tid < 8){
      // phase 2a: damping one-pole scans + comb writes (lane = comb)
      int k = tid;
      int L = LC[k], off = COFF[k], base = cbb[k];
      float s = sreg;
      int n1 = L - base; if (n1 > Bc) n1 = Bc;
      int i = 0;
      for (; i<n1; i++){
        float o = outS[k*225+i];
        s = fmaf(damp, s, omd*o);
        cb[off+base+i] = fmaf(fb, s, xts[i]);
      }
      for (; i<Bc; i++){
        float o = outS[k*225+i];
        s = fmaf(damp, s, omd*o);
        cb[off+base+i-L] = fmaf(fb, s, xts[i]);
      }
      sreg = s;
    } else if (tid >= 64){
      // phase 2b: comb sum + allpass chain + output (per-sample, no aliasing)
      for (int i=tid-64; i<Bc; i+=192){
        float a = outS[i];
        #pragma unroll
        for (int k=1;k<8;k++) a += outS[k*225+i];
        #pragma unroll
        for (int j=0;j<4;j++){
          int idx = abb[j]+i; if (idx>=LA[j]) idx-=LA[j];
          float bv = ab[AOFF[j]+idx];
          ab[AOFF[j]+idx] = fmaf(0.5f, bv, a);
          a = bv - a;
        }
        Bout[t0+i] = fmaf(a, wet1, xts[i]*dryk);
      }
    }
    #pragma unroll
    for (int k=0;k<8;k++){ cbb[k]+=225; if (cbb[k]>=LC[k]) cbb[k]-=LC[k]; }
    #pragma unroll
    for (int j=0;j<4;j++){ abb[j]+=225; if (abb[j]>=LA[j]) abb[j]-=LA[j]; }
    __syncthreads();
  }
}

// ---------------- pan mix ----------------

__global__ void k_mix(const float* __restrict__ ws, float* __restrict__ out){
  int id = blockIdx.x*256 + threadIdx.x;   // 4*65536
  int t = id & (T-1), b = id >> 16;
  const float* Bv = ws + OFS_B + b*8*T + t;
  const float* P = ws + OFS_P;
  float s0=0.0f, s1=0.0f;
  #pragma unroll
  for (int n=0;n<8;n++){
    float v = Bv[n*T];
    int ch = b*8+n;
    s0 = fmaf(v, P[ch*64+38], s0);
    s1 = fmaf(v, P[ch*64+39], s1);
  }
  out[b*2*T + t]     = s0;
  out[b*2*T + T + t] = s1;
}

extern "C" void kernel_launch(void* const* d_in, const int* in_sizes, int n_in,
                              void* d_out, int out_size, void* d_ws, size_t ws_size,
                              hipStream_t stream) {
  const float* x = (const float*)d_in[0];
  const float* p = (const float*)d_in[1];
  float* out = (float*)d_out;
  float* ws  = (float*)d_ws;

  k_params<<<1, 64, 0, stream>>>(p, ws, out + 4*2*T);
  k_chunk1<<<70, 64, 0, stream>>>(x, ws);
  k_chunk2<<<1, 64, 0, stream>>>(ws);
  k_chunk3<<<64, 64, 0, stream>>>(x, ws);
  k_comp  <<<1, 64, 0, stream>>>(ws);
  k_verb  <<<NCH, 256, 0, stream>>>(ws);
  k_mix   <<<(4*T)/256, 256, 0, stream>>>(ws, out);
}

// Round 3
// 2364.626 us; speedup vs baseline: 3.6600x; 3.6600x over previous
//
#include <hip/hip_runtime.h>
#include <math.h>

#define T 65536
#define NCH 32
#define LCHUNK 512
#define CCHUNK 128

// ws layout (float offsets). Total ~17.2 MB of d_ws.
#define OFS_A 0         // 32*65536: biquad out
#define OFS_B 2097152   // 32*65536: compressor target -> gain g (in-place) -> reverb out (in-place)
#define OFS_P 4194304   // 32*64 derived params
#define OFS_M 4196352   // 32*144 chunk transition matrices (columns)
#define OFS_V 4200960   // 32*128*12 chunk zero-state finals
#define OFS_Z 4250112   // 32*128*12 chunk initial states

// ---------------- param kernel (also writes p_out) ----------------

__device__ void norm_store(double b0,double b1,double b2,double a0,double a1,double a2,
                           double* B, double* A1, double* A2, int k){
  B[k*3+0]=b0/a0; B[k*3+1]=b1/a0; B[k*3+2]=b2/a0; A1[k]=a1/a0; A2[k]=a2/a0;
}

__device__ void shelf_coefs(double fc, double g, double s, double* B, double* A1, double* A2, int k){
  double A  = pow(10.0, g/40.0);
  double w  = 2.0*3.14159265358979323846*fc/44100.0;
  double cw = cos(w);
  double al = sin(w)*0.70710678118654752;
  double sq = 2.0*sqrt(A)*al;
  double b0 = A*((A+1.0) + s*(A-1.0)*cw + sq);
  double b1 = -2.0*s*A*((A-1.0) + s*(A+1.0)*cw);
  double b2 = A*((A+1.0) + s*(A-1.0)*cw - sq);
  double a0 = (A+1.0) - s*(A-1.0)*cw + sq;
  double a1 = 2.0*s*((A-1.0) - s*(A+1.0)*cw);
  double a2 = (A+1.0) - s*(A-1.0)*cw - sq;
  norm_store(b0,b1,b2,a0,a1,a2,B,A1,A2,k);
}

__device__ void peak_coefs(double fc, double g, double q, double* B, double* A1, double* A2, int k){
  double A  = pow(10.0, g/40.0);
  double w  = 2.0*3.14159265358979323846*fc/44100.0;
  double cw = cos(w);
  double al = sin(w)/(2.0*q);
  norm_store(1.0+al*A, -2.0*cw, 1.0-al*A, 1.0+al/A, -2.0*cw, 1.0-al/A, B,A1,A2,k);
}

__global__ void k_params(const float* __restrict__ p, float* __restrict__ ws, float* __restrict__ pout){
  int ch = threadIdx.x;
  if (ch >= NCH) return;
  const float* pf = p + ch*24;
  float f[24];
  #pragma unroll
  for (int j=0;j<24;j++) f[j]=pf[j];

  double gain_in = (double)f[0]*60.0 - 48.0;
  double hp_fc  = (double)f[1]*350.0;
  double lp_fc  = (double)f[2]*19000.0 + 3000.0;
  double hs_fc  = (double)f[3]*14500.0 + 1500.0;
  double hs_g   = (double)f[4]*30.0 - 15.0;
  double ls_fc  = (double)f[5]*420.0 + 30.0;
  double ls_g   = (double)f[6]*30.0 - 15.0;
  double mh_fc  = (double)f[7]*6400.0 + 600.0;
  double mh_g   = (double)f[8]*30.0 - 15.0;
  double mh_q   = (double)f[9]*2.5 + 0.5;
  double ml_fc  = (double)f[10]*2300.0 + 200.0;
  double ml_g   = (double)f[11]*30.0 - 15.0;
  double ml_q   = (double)f[12]*2.5 + 0.5;
  double c_thr  = (double)f[13]*30.0 - 20.0;
  double c_rat  = (double)f[14]*19.0 + 1.0;
  double c_att  = (double)f[15]*29.0 + 1.0;
  double c_rel  = (double)f[16]*3900.0 + 100.0;
  double gain_out=(double)f[22]*60.0 - 48.0;
  double pan    = (double)f[23]*0.4 + 0.3;

  double B[18], A1[6], A2[6];
  // section 0: hp
  { double K = tan(3.14159265358979323846*hp_fc/44100.0);
    double a1=(K-1.0)/(K+1.0), b0=1.0/(1.0+K);
    B[0]=b0; B[1]=-b0; B[2]=0.0; A1[0]=a1; A2[0]=0.0; }
  // section 1: lp
  { double K = tan(3.14159265358979323846*lp_fc/44100.0);
    double a1=(K-1.0)/(K+1.0), b0=K/(1.0+K);
    B[3]=b0; B[4]=b0; B[5]=0.0; A1[1]=a1; A2[1]=0.0; }
  shelf_coefs(hs_fc, hs_g,  1.0, B, A1, A2, 2);
  shelf_coefs(ls_fc, ls_g, -1.0, B, A1, A2, 3);
  peak_coefs (mh_fc, mh_g, mh_q, B, A1, A2, 4);
  peak_coefs (ml_fc, ml_g, ml_q, B, A1, A2, 5);

  double gin = pow(10.0, gain_in/20.0);
  B[0]*=gin; B[1]*=gin; B[2]*=gin;  // fold input gain into section 0

  float* Pc = ws + OFS_P + ch*64;
  #pragma unroll
  for (int k=0;k<6;k++){
    Pc[k]    = (float)B[k*3+0];
    Pc[6+k]  = (float)B[k*3+1];
    Pc[12+k] = (float)B[k*3+2];
    Pc[18+k] = (float)A1[k];
    Pc[24+k] = (float)A2[k];
  }
  Pc[30] = (float)c_thr;
  Pc[31] = (float)(1.0 - 1.0/c_rat);
  Pc[32] = (float)exp(-1.0/(c_att*0.001*44100.0));
  Pc[33] = (float)exp(-1.0/(c_rel*0.001*44100.0));
  double fb   = (double)f[17]*0.28 + 0.7;
  double damp = (double)f[18]*0.4;
  double wet1 = 3.0*(double)f[19]*0.5*(1.0+(double)f[21]);
  double dryg = 2.0*(double)f[20];
  double gout = pow(10.0, gain_out/20.0);
  Pc[34] = (float)fb;
  Pc[35] = (float)damp;
  Pc[36] = (float)(wet1*gout);
  Pc[37] = (float)(dryg*gout/0.015);   // applied to (xt*0.015) stored in LDS
  Pc[38] = (float)cos(pan*1.57079632679489662);
  Pc[39] = (float)sin(pan*1.57079632679489662);

  float* po = pout + ch*24;
  po[0]=(float)gain_in; po[1]=(float)hp_fc; po[2]=(float)lp_fc; po[3]=(float)hs_fc;
  po[4]=(float)hs_g; po[5]=(float)ls_fc; po[6]=(float)ls_g; po[7]=(float)mh_fc;
  po[8]=(float)mh_g; po[9]=(float)mh_q; po[10]=(float)ml_fc; po[11]=(float)ml_g;
  po[12]=(float)ml_q; po[13]=(float)c_thr; po[14]=(float)c_rat; po[15]=(float)c_att;
  po[16]=(float)c_rel; po[17]=f[17]; po[18]=f[18]; po[19]=f[19]; po[20]=f[20];
  po[21]=f[21]; po[22]=(float)gain_out; po[23]=(float)pan;
}

// ---------------- biquad cascade: chunked linear scan ----------------

__device__ __forceinline__ float bq_step(const float* b0, const float* b1, const float* b2,
                                         const float* a1, const float* a2,
                                         float* z1, float* z2, float s){
  #pragma unroll
  for (int k=0;k<6;k++){
    float y = fmaf(b0[k], s, z1[k]);
    z1[k] = fmaf(b1[k], s, fmaf(-a1[k], y, z2[k]));
    z2[k] = fmaf(b2[k], s, -a2[k]*y);
    s = y;
  }
  return s;
}

__device__ __forceinline__ void load_coefs(const float* Pc, float* b0, float* b1, float* b2,
                                           float* a1, float* a2){
  #pragma unroll
  for (int k=0;k<6;k++){
    b0[k]=Pc[k]; b1[k]=Pc[6+k]; b2[k]=Pc[12+k]; a1[k]=Pc[18+k]; a2[k]=Pc[24+k];
  }
}

// pass 1: per-chunk zero-state run -> v; unit-state zero-input runs -> M columns
__global__ void k_chunk1(const float* __restrict__ x, float* __restrict__ ws){
  int tg = blockIdx.x*64 + threadIdx.x;      // 32 * 140 tasks
  int ch = tg / 140, sub = tg % 140;
  if (ch >= NCH) return;
  const float* Pc = ws + OFS_P + ch*64;
  float b0[6],b1[6],b2[6],a1[6],a2[6];
  load_coefs(Pc,b0,b1,b2,a1,a2);
  float z1[6]={0,0,0,0,0,0}, z2[6]={0,0,0,0,0,0};

  if (sub < CCHUNK){
    const float4* xp = (const float4*)(x + ch*T + sub*LCHUNK);
    for (int j=0;j<LCHUNK/4;j++){
      float4 v = xp[j];
      bq_step(b0,b1,b2,a1,a2,z1,z2,v.x);
      bq_step(b0,b1,b2,a1,a2,z1,z2,v.y);
      bq_step(b0,b1,b2,a1,a2,z1,z2,v.z);
      bq_step(b0,b1,b2,a1,a2,z1,z2,v.w);
    }
    float* vo = ws + OFS_V + (ch*CCHUNK + sub)*12;
    #pragma unroll
    for (int k=0;k<6;k++){ vo[2*k]=z1[k]; vo[2*k+1]=z2[k]; }
  } else {
    int j = sub - CCHUNK;                    // unit state index 0..11
    if ((j & 1)==0) z1[j>>1]=1.0f; else z2[j>>1]=1.0f;
    for (int t=0;t<LCHUNK;t++) bq_step(b0,b1,b2,a1,a2,z1,z2,0.0f);
    float* mo = ws + OFS_M + ch*144 + j*12;  // column j
    #pragma unroll
    for (int k=0;k<6;k++){ mo[2*k]=z1[k]; mo[2*k+1]=z2[k]; }
  }
}

// pass 2: serial chunk-boundary state propagation (one wave, lane=channel)
__global__ void k_chunk2(float* __restrict__ ws){
  int ch = threadIdx.x;
  if (ch >= NCH) return;
  const float* M = ws + OFS_M + ch*144;
  const float* V = ws + OFS_V + ch*CCHUNK*12;
  float*       Z = ws + OFS_Z + ch*CCHUNK*12;
  float z[12];
  #pragma unroll
  for (int i=0;i<12;i++) z[i]=0.0f;
  for (int c=0;c<CCHUNK;c++){
    #pragma unroll
    for (int i=0;i<12;i++) Z[c*12+i]=z[i];
    float zn[12];
    #pragma unroll
    for (int i=0;i<12;i++) zn[i]=V[c*12+i];
    #pragma unroll
    for (int j=0;j<12;j++){
      float zj = z[j];
      #pragma unroll
      for (int i=0;i<12;i++) zn[i] = fmaf(M[j*12+i], zj, zn[i]);
    }
    #pragma unroll
    for (int i=0;i<12;i++) z[i]=zn[i];
  }
}

// pass 3: re-run chunks with correct init; write biquad out (A) + compressor target (B)
__global__ void k_chunk3(const float* __restrict__ x, float* __restrict__ ws){
  int tg = blockIdx.x*64 + threadIdx.x;      // 4096
  int ch = tg >> 7, c = tg & (CCHUNK-1);
  const float* Pc = ws + OFS_P + ch*64;
  float b0[6],b1[6],b2[6],a1[6],a2[6];
  load_coefs(Pc,b0,b1,b2,a1,a2);
  float thr = Pc[30], rt = Pc[31];
  const float* Zi = ws + OFS_Z + (ch*CCHUNK + c)*12;
  float z1[6], z2[6];
  #pragma unroll
  for (int k=0;k<6;k++){ z1[k]=Zi[2*k]; z2[k]=Zi[2*k+1]; }
  const float4* xp = (const float4*)(x + ch*T + c*LCHUNK);
  float4* Ao = (float4*)(ws + OFS_A + ch*T + c*LCHUNK);
  float4* Bo = (float4*)(ws + OFS_B + ch*T + c*LCHUNK);
  for (int j=0;j<LCHUNK/4;j++){
    float4 v = xp[j], ya, tb;
    ya.x = bq_step(b0,b1,b2,a1,a2,z1,z2,v.x);
    ya.y = bq_step(b0,b1,b2,a1,a2,z1,z2,v.y);
    ya.z = bq_step(b0,b1,b2,a1,a2,z1,z2,v.z);
    ya.w = bq_step(b0,b1,b2,a1,a2,z1,z2,v.w);
    tb.x = fminf(0.0f, (thr - 6.0205999132796239f*log2f(fabsf(ya.x)+1e-6f))*rt);
    tb.y = fminf(0.0f, (thr - 6.0205999132796239f*log2f(fabsf(ya.y)+1e-6f))*rt);
    tb.z = fminf(0.0f, (thr - 6.0205999132796239f*log2f(fabsf(ya.z)+1e-6f))*rt);
    tb.w = fminf(0.0f, (thr - 6.0205999132796239f*log2f(fabsf(ya.w)+1e-6f))*rt);
    Ao[j]=ya; Bo[j]=tb;
  }
}

// ---------------- compressor scan: g only, in-place over B ----------------
// coef = (tgt<g) ? aA : aR and aA<aR  =>  g' = min(aA*g+(1-aA)t, aR*g+(1-aR)t)
// Register double-buffer (64-sample blocks) hides global-load latency;
// gain application (exp2) is fused into k_verb phase 1.

#define CSTEP(v) { float bA=kA*(v), bR=kR*(v); \
                   g = fminf(fmaf(aA,g,bA), fmaf(aR,g,bR)); (v)=g; }

__global__ void k_comp(float* __restrict__ ws){
  int ch = threadIdx.x;
  if (ch >= NCH) return;
  const float* Pc = ws + OFS_P + ch*64;
  float aA = Pc[32], aR = Pc[33];
  float kA = 1.0f - aA, kR = 1.0f - aR;
  float4* Bq = (float4*)(ws + OFS_B + ch*T);
  float4 b0[16], b1[16];
  #pragma unroll
  for (int j=0;j<16;j++) b0[j] = Bq[j];
  float g = 0.0f;
  for (int blk=0; blk<T/64; blk+=2){
    // prefetch blk+1
    #pragma unroll
    for (int j=0;j<16;j++) b1[j] = Bq[(blk+1)*16+j];
    // compute blk from b0, store g in place
    #pragma unroll
    for (int j=0;j<16;j++){
      float4 t = b0[j];
      CSTEP(t.x) CSTEP(t.y) CSTEP(t.z) CSTEP(t.w)
      Bq[blk*16+j] = t;
    }
    // prefetch blk+2
    if (blk+2 < T/64){
      #pragma unroll
      for (int j=0;j<16;j++) b0[j] = Bq[(blk+2)*16+j];
    }
    // compute blk+1 from b1
    #pragma unroll
    for (int j=0;j<16;j++){
      float4 t = b1[j];
      CSTEP(t.x) CSTEP(t.y) CSTEP(t.z) CSTEP(t.w)
      Bq[(blk+1)*16+j] = t;
    }
  }
}

// ---------------- freeverb: 225-sample blocks, parallel truncated damping FIR ----
// damp <= 0.4 so the damping one-pole has ~16-sample memory: for lane i,
//   s_i = sum_{d=0..min(i,15)} damp^d * c_{i-d}  +  damp^(i+1) * s_prev
// exact for i<16 (carry term), truncation error <= 0.4^16/(1-fb) ~ 2e-5 otherwise.
// Gain application (compressor) fused into phase 1.

#define VH 16

__global__ __launch_bounds__(256) void k_verb(float* __restrict__ ws){
  const int LC[8] = {1116,1188,1277,1356,1422,1491,1557,1617};
  const int COFF[8] = {0,1116,2304,3581,4937,6359,7850,9407};
  const int LA[4] = {556,441,341,225};
  const int AOFF[4] = {0,556,997,1338};
  int ch = blockIdx.x, tid = threadIdx.x;
  __shared__ float cb[11024];
  __shared__ float ab[1563];
  __shared__ float outC[8*226];   // c = (1-damp)*comb_out, k-major (conflict-free)
  __shared__ float xts[225];
  __shared__ float accS[225];
  __shared__ float sP[2][8];      // ping-pong damping-state carry
  const float* Pc = ws + OFS_P + ch*64;
  float fb = Pc[34], damp = Pc[35], wet1 = Pc[36], dryk = Pc[37];
  float omd = 1.0f - damp;
  const float* Axf = ws + OFS_A + ch*T;
  float* Bio = ws + OFS_B + ch*T;   // in: g  out: reverb result
  for (int i=tid;i<11024;i+=256) cb[i]=0.0f;
  for (int i=tid;i<1563;i+=256)  ab[i]=0.0f;
  if (tid < 16) sP[tid>>3][tid&7] = 0.0f;
  // per-lane FIR weights and carry power
  float w[VH];
  { float pw = 1.0f;
    #pragma unroll
    for (int d=0; d<VH; d++){ w[d] = (tid>=d) ? pw : 0.0f; pw *= damp; }
  }
  float cp = 1.0f;
  for (int j=0; j<=tid; j++) cp *= damp;   // damp^(tid+1), one-time
  int cbb[8] = {0,0,0,0,0,0,0,0};
  int abb[4] = {0,0,0,0};
  __syncthreads();

  int blk = 0;
  for (int t0=0; t0<T; t0+=225, blk++){
    int Bc = (T - t0 < 225) ? (T - t0) : 225;
    // phase 1: apply compressor gain, gather comb outputs, store c and acc
    if (tid < Bc){
      float xv = Axf[t0+tid];
      float gv = Bio[t0+tid];
      float xt = xv * exp2f(gv*0.16609640474436813f) * 0.015f;
      xts[tid] = xt;
      float acc = 0.0f;
      #pragma unroll
      for (int k=0;k<8;k++){
        int idx = cbb[k]+tid; if (idx>=LC[k]) idx-=LC[k];
        float o = cb[COFF[k]+idx];
        outC[k*226+tid] = omd*o;
        acc += o;
      }
      accS[tid] = acc;
    }
    __syncthreads();
    // phase 2: parallel damping FIR + comb writes + allpass chain + output
    if (tid < Bc){
      int rp = blk & 1;
      float s[8];
      #pragma unroll
      for (int k=0;k<8;k++) s[k] = cp * sP[rp][k];
      #pragma unroll
      for (int d=0; d<VH; d++){
        int r = tid - d; r = r < 0 ? 0 : r;
        #pragma unroll
        for (int k=0;k<8;k++) s[k] = fmaf(w[d], outC[k*226+r], s[k]);
      }
      float xt = xts[tid];
      #pragma unroll
      for (int k=0;k<8;k++){
        int idx = cbb[k]+tid; if (idx>=LC[k]) idx-=LC[k];
        cb[COFF[k]+idx] = fmaf(fb, s[k], xt);
      }
      if (tid == Bc-1){
        #pragma unroll
        for (int k=0;k<8;k++) sP[rp^1][k] = s[k];
      }
      float a = accS[tid];
      #pragma unroll
      for (int j=0;j<4;j++){
        int idx = abb[j]+tid; if (idx>=LA[j]) idx-=LA[j];
        float bv = ab[AOFF[j]+idx];
        ab[AOFF[j]+idx] = fmaf(0.5f, bv, a);
        a = bv - a;
      }
      Bio[t0+tid] = fmaf(a, wet1, xt*dryk);
    }
    #pragma unroll
    for (int k=0;k<8;k++){ cbb[k]+=225; if (cbb[k]>=LC[k]) cbb[k]-=LC[k]; }
    #pragma unroll
    for (int j=0;j<4;j++){ abb[j]+=225; if (abb[j]>=LA[j]) abb[j]-=LA[j]; }
    __syncthreads();
  }
}

// ---------------- pan mix ----------------

__global__ void k_mix(const float* __restrict__ ws, float* __restrict__ out){
  int id = blockIdx.x*256 + threadIdx.x;   // 4*65536
  int t = id & (T-1), b = id >> 16;
  const float* Bv = ws + OFS_B + b*8*T + t;
  const float* P = ws + OFS_P;
  float s0=0.0f, s1=0.0f;
  #pragma unroll
  for (int n=0;n<8;n++){
    float v = Bv[n*T];
    int ch = b*8+n;
    s0 = fmaf(v, P[ch*64+38], s0);
    s1 = fmaf(v, P[ch*64+39], s1);
  }
  out[b*2*T + t]     = s0;
  out[b*2*T + T + t] = s1;
}

extern "C" void kernel_launch(void* const* d_in, const int* in_sizes, int n_in,
                              void* d_out, int out_size, void* d_ws, size_t ws_size,
                              hipStream_t stream) {
  const float* x = (const float*)d_in[0];
  const float* p = (const float*)d_in[1];
  float* out = (float*)d_out;
  float* ws  = (float*)d_ws;

  k_params<<<1, 64, 0, stream>>>(p, ws, out + 4*2*T);
  k_chunk1<<<70, 64, 0, stream>>>(x, ws);
  k_chunk2<<<1, 64, 0, stream>>>(ws);
  k_chunk3<<<64, 64, 0, stream>>>(x, ws);
  k_comp  <<<1, 64, 0, stream>>>(ws);
  k_verb  <<<NCH, 256, 0, stream>>>(ws);
  k_mix   <<<(4*T)/256, 256, 0, stream>>>(ws, out);
}